// Round 1
// baseline (132.159 us; speedup 1.0000x reference)
//
#include <hip/hip_runtime.h>
#include <math.h>

// B=4, N=128, H=W=32, C=64.  out[b][j][n] = sigmoid(wl[j,:] . mean_hw MLP(...) + bl[j])
//
// R9: REGISTER-RESIDENT LAYER CHAIN. R8 post-mortem: kernel ~30us of the
// 109us window (2x 268MB poison fills = ~79us harness floor); DS ~51% /
// VALU 44% / MfmaUtil ~18% -- the C->B activation transform through LDS
// (store_tile + bf reads + repack) dominates.
// Fix: switch 16x16x32 -> 16x16x16 MFMA. Its B layout (n=lane&15,
// k=(lane>>4)*4+j) EXACTLY matches the C/D layout (col=lane&15,
// row=(lane>>4)*4+reg): acc[mt] of layer l IS the ks=mt B-fragment of
// layer l+1 after in-register leaky+cvt. Zero activation LDS traffic,
// zero cross-lane movement. 2x MFMA count (K=16) is free at 18% util.
//   - weights w2..w5 in 128 VGPRs (staged once via 32KB LDS broadcast so
//     global fetch is once per block, not once per wave)
//   - biases in LDS, ds_read_b128 straight into acc init (DS pipe idle now)
//   - image pixels prefetched one tile ahead
// Tripwire: WRITE_SIZE must stay ~0 (no spill; est ~210 VGPR, cap 256 @ 2/EU).

typedef float  f32x4  __attribute__((ext_vector_type(4)));
typedef f32x4  f32x4a __attribute__((may_alias));
typedef __bf16 bf16x4 __attribute__((ext_vector_type(4)));
typedef bf16x4 bf16x4a __attribute__((may_alias));
typedef short  s16x4  __attribute__((ext_vector_type(4)));
typedef float  floata __attribute__((may_alias));

static __device__ __forceinline__ f32x4 MFMA16(bf16x4 a, bf16x4 b, f32x4 c) {
    return __builtin_amdgcn_mfma_f32_16x16x16bf16_1k(
        __builtin_bit_cast(s16x4, a), __builtin_bit_cast(s16x4, b), c, 0, 0, 0);
}

static __device__ __forceinline__ bf16x4 cvt4(f32x4 v) {
    bf16x4 r;
    r[0] = (__bf16)v[0]; r[1] = (__bf16)v[1];
    r[2] = (__bf16)v[2]; r[3] = (__bf16)v[3];
    return r;
}

__global__ __launch_bounds__(256, 2) void mlp_mfma_kernel(
    const float* __restrict__ image,   // [4,3,32,32]
    const float* __restrict__ coords,  // [4,128,2]
    const float* __restrict__ w1, const float* __restrict__ b1,   // [64,7],[64]
    const float* __restrict__ w2, const float* __restrict__ b2,   // [64,64],[64]
    const float* __restrict__ w3, const float* __restrict__ b3,
    const float* __restrict__ w4, const float* __restrict__ b4,
    const float* __restrict__ w5, const float* __restrict__ b5,
    const float* __restrict__ wl, const float* __restrict__ bl,   // [3,64],[3]
    float* __restrict__ out)           // [4,3,128]
{
    // WF: [l][frag=mt*4+ks][lane] x bf16x4  = 4*16*64*4 bf16 = 32 KB
    __shared__ __align__(16) __bf16 WF[16384];
    __shared__ __align__(16) float  POOL[4][1024];   // [wave][ch*16+col] 16 KB
    __shared__ float BL[320];                         // [layer][64]

    const int tid  = threadIdx.x;
    const int wave = tid >> 6;
    const int lane = tid & 63;
    const int c15  = lane & 15;
    const int q    = lane >> 4;
    const int bn   = blockIdx.x;
    const int b    = bn >> 7;

    const float* Ws[4] = {w2, w3, w4, w5};

    // ---- stage weight A-frags (bf16) into LDS: wave w converts layer w.
    // A frag (mt,ks): lane holds W[mt*16+c15][ks*16+4q+j], j=0..3.
    {
        const float* Wsrc = Ws[wave];
        #pragma unroll
        for (int f = 0; f < 16; ++f) {
            const int mt = f >> 2, ks = f & 3;
            f32x4 v = *(const f32x4a*)(Wsrc + (mt * 16 + c15) * 64 + ks * 16 + 4 * q);
            *(bf16x4a*)&WF[((wave * 16 + f) * 64 + lane) * 4] = cvt4(v);
        }
    }
    if (tid < 64) {
        BL[tid]       = b1[tid];
        BL[64 + tid]  = b2[tid];
        BL[128 + tid] = b3[tid];
        BL[192 + tid] = b4[tid];
        BL[256 + tid] = b5[tid];
    }
    __syncthreads();

    // ---- hoist ALL weights into registers (4l x 4mt x 4ks x 8B = 128 VGPR)
    bf16x4 wf[4][4][4];
    #pragma unroll
    for (int l = 0; l < 4; ++l)
        #pragma unroll
        for (int mt = 0; mt < 4; ++mt)
            #pragma unroll
            for (int ks = 0; ks < 4; ++ks)
                wf[l][mt][ks] = *(const bf16x4a*)
                    &WF[((l * 16 + mt * 4 + ks) * 64 + lane) * 4];

    // ---- layer-1 A-frags (K=16, channels 0..6 used): w1[row][k], k=4q+j
    bf16x4 a1[4];
    #pragma unroll
    for (int mt = 0; mt < 4; ++mt)
        #pragma unroll
        for (int j = 0; j < 4; ++j) {
            const int k = 4 * q + j;
            float v = (k < 7) ? w1[(mt * 16 + c15) * 7 + k] : 0.0f;
            a1[mt][j] = (__bf16)v;
        }

    const float cx = coords[2 * bn + 0];
    const float cy = coords[2 * bn + 1];
    const float* img = image + b * 3072;

    // ---- loop-invariant pieces of the layer-1 B-fragment.
    // B1 lane (q,c15): q=0 -> [img0,img1,img2,row], q=1 -> [col,cx,cy,0], else 0.
    // col = (hw&31)/31 depends only on tile parity; row is lane-uniform per tile.
    const float inv31 = 1.0f / 31.0f;
    const bool  q0  = (q == 0);
    const float g0e = (q == 1) ? (float)c15 * inv31        : 0.0f;
    const float g0o = (q == 1) ? (float)(c15 + 16) * inv31 : 0.0f;
    const float g1  = (q == 1) ? cx : 0.0f;
    const float g2  = (q == 1) ? cy : 0.0f;

    f32x4 pool[4];
    #pragma unroll
    for (int mt = 0; mt < 4; ++mt) pool[mt] = (f32x4){0.f, 0.f, 0.f, 0.f};

    // prefetch pixels for tile 0 (hw = wave*256 + t*16 + c15)
    float p0, p1, p2;
    {
        const int hw = wave * 256 + c15;
        p0 = img[hw]; p1 = img[1024 + hw]; p2 = img[2048 + hw];
    }

    #pragma unroll 1
    for (int t = 0; t < 16; ++t) {      // 16 tiles x 16 px per wave
        // ---- build layer-1 B fragment from prefetched pixels
        const float rowv = (float)(wave * 8 + (t >> 1)) * inv31;
        const float f0 = q0 ? p0 : ((t & 1) ? g0o : g0e);
        const float f1 = q0 ? p1 : g1;
        const float f2 = q0 ? p2 : g2;
        const float f3 = q0 ? rowv : 0.0f;
        bf16x4 B1;
        B1[0] = (__bf16)f0; B1[1] = (__bf16)f1;
        B1[2] = (__bf16)f2; B1[3] = (__bf16)f3;

        // ---- prefetch next tile's pixels (hide HBM/L2 under the layer chain)
        {
            const int tt = (t < 15) ? (t + 1) : 15;
            const int hw = wave * 256 + tt * 16 + c15;
            p0 = img[hw]; p1 = img[1024 + hw]; p2 = img[2048 + hw];
        }

        // ======== layer 1 (acc init = bias from LDS) ========
        f32x4 acc[4];
        #pragma unroll
        for (int mt = 0; mt < 4; ++mt)
            acc[mt] = *(const f32x4a*)&BL[mt * 16 + 4 * q];
        #pragma unroll
        for (int mt = 0; mt < 4; ++mt)
            acc[mt] = MFMA16(a1[mt], B1, acc[mt]);

        // ======== layers 2..5 — fully register-resident chaining ========
        bf16x4 Bf[4];
        #pragma unroll
        for (int l = 0; l < 4; ++l) {
            // transition: leaky + cvt; acc[mt] -> B-fragment ks=mt (same lane!)
            #pragma unroll
            for (int mt = 0; mt < 4; ++mt) {
                f32x4 v = acc[mt];
                #pragma unroll
                for (int r = 0; r < 4; ++r) v[r] = fmaxf(v[r], 0.1f * v[r]);
                Bf[mt] = cvt4(v);
            }
            #pragma unroll
            for (int mt = 0; mt < 4; ++mt)
                acc[mt] = *(const f32x4a*)&BL[(l + 1) * 64 + mt * 16 + 4 * q];
            #pragma unroll
            for (int ks = 0; ks < 4; ++ks)      // ks outer: 4 independent chains
                #pragma unroll
                for (int mt = 0; mt < 4; ++mt)
                    acc[mt] = MFMA16(wf[l][mt][ks], Bf[ks], acc[mt]);
        }

        // ---- final leaky + pool accumulate (registers only)
        #pragma unroll
        for (int mt = 0; mt < 4; ++mt)
            #pragma unroll
            for (int r = 0; r < 4; ++r) {
                const float v = acc[mt][r];
                pool[mt][r] += fmaxf(v, 0.1f * v);
            }
    }

    // ---- pool partials -> this wave's POOL region: [ch][col16]
    floata* Xf = &POOL[wave][0];
    #pragma unroll
    for (int mt = 0; mt < 4; ++mt)
        #pragma unroll
        for (int r = 0; r < 4; ++r)
            Xf[(mt * 16 + 4 * q + r) * 16 + c15] = pool[mt][r];

    __syncthreads();

    // ---- block reduce (4 waves x 16 cols) + head + sigmoid
    if (tid < 64) {
        const int c = tid;
        float s = 0.0f;
        #pragma unroll
        for (int w = 0; w < 4; ++w) {
            const floata* P = &POOL[w][0];
            #pragma unroll
            for (int c4 = 0; c4 < 4; ++c4) {
                f32x4 v = *(const f32x4a*)&P[c * 16 + c4 * 4];
                s += v[0] + v[1] + v[2] + v[3];
            }
        }
        const float p = s * (1.0f / 1024.0f);
        float s0 = wl[c] * p;
        float s1 = wl[64 + c] * p;
        float s2 = wl[128 + c] * p;
        #pragma unroll
        for (int off = 32; off > 0; off >>= 1) {
            s0 += __shfl_down(s0, off, 64);
            s1 += __shfl_down(s1, off, 64);
            s2 += __shfl_down(s2, off, 64);
        }
        if (c == 0) {
            const int n = bn & 127;
            out[(b * 3 + 0) * 128 + n] = 1.0f / (1.0f + expf(-(bl[0] + s0)));
            out[(b * 3 + 1) * 128 + n] = 1.0f / (1.0f + expf(-(bl[1] + s1)));
            out[(b * 3 + 2) * 128 + n] = 1.0f / (1.0f + expf(-(bl[2] + s2)));
        }
    }
}

extern "C" void kernel_launch(void* const* d_in, const int* in_sizes, int n_in,
                              void* d_out, int out_size, void* d_ws, size_t ws_size,
                              hipStream_t stream) {
    const float* image  = (const float*)d_in[0];
    const float* coords = (const float*)d_in[1];
    const float* w1 = (const float*)d_in[2];
    const float* b1 = (const float*)d_in[3];
    const float* w2 = (const float*)d_in[4];
    const float* b2 = (const float*)d_in[5];
    const float* w3 = (const float*)d_in[6];
    const float* b3 = (const float*)d_in[7];
    const float* w4 = (const float*)d_in[8];
    const float* b4 = (const float*)d_in[9];
    const float* w5 = (const float*)d_in[10];
    const float* b5 = (const float*)d_in[11];
    const float* wl = (const float*)d_in[12];
    const float* bl = (const float*)d_in[13];
    float* out = (float*)d_out;

    mlp_mfma_kernel<<<dim3(512), dim3(256), 0, stream>>>(
        image, coords, w1, b1, w2, b2, w3, b3, w4, b4, w5, b5, wl, bl, out);
}